// Round 1
// baseline (394.266 us; speedup 1.0000x reference)
//
#include <hip/hip_runtime.h>
#include <math.h>

#define LRELU_ALPHA 0.2f

constexpr int Bc = 8;
constexpr int Nc = 2048;
constexpr int Hc = 128;
constexpr int ROWS = Bc * Nc;   // 16384

// Kernel 1: Wh = inp @ W  (+ Wh1 = Wh@a[:H], Wh2 = Wh@a[H:])
// One wave per output row; lane holds h=lane and h=lane+64.
__global__ __launch_bounds__(256) void wh_kernel(
    const float* __restrict__ inp, const float* __restrict__ W,
    const float* __restrict__ a, float* __restrict__ Wh,
    float* __restrict__ Wh1, float* __restrict__ Wh2) {
  const int wave = threadIdx.x >> 6;
  const int lane = threadIdx.x & 63;
  const int row  = blockIdx.x * 4 + wave;
  if (row >= ROWS) return;

  const float* __restrict__ x = inp + (size_t)row * Hc;
  float acc0 = 0.f, acc1 = 0.f;
#pragma unroll 8
  for (int k = 0; k < Hc; ++k) {
    const float xk = x[k];                       // wave-uniform broadcast
    acc0 = fmaf(xk, W[k * Hc + lane], acc0);
    acc1 = fmaf(xk, W[k * Hc + 64 + lane], acc1);
  }
  Wh[(size_t)row * Hc + lane]      = acc0;
  Wh[(size_t)row * Hc + 64 + lane] = acc1;

  // row dot with a1 and a2
  float p1 = acc0 * a[lane] + acc1 * a[64 + lane];
  float p2 = acc0 * a[Hc + lane] + acc1 * a[Hc + 64 + lane];
#pragma unroll
  for (int off = 32; off > 0; off >>= 1) {
    p1 += __shfl_xor(p1, off);
    p2 += __shfl_xor(p2, off);
  }
  if (lane == 0) { Wh1[row] = p1; Wh2[row] = p2; }
}

// Kernel 2: fused masked-softmax + attention@Wh + ELU, one wave per row.
// Online softmax over nonzeros of A row (plus forced diagonal).
__global__ __launch_bounds__(256) void attn_kernel(
    const float* __restrict__ A, const float* __restrict__ Wh,
    const float* __restrict__ Wh1, const float* __restrict__ Wh2,
    float* __restrict__ out) {
  const int wave = threadIdx.x >> 6;
  const int lane = threadIdx.x & 63;
  const int row  = blockIdx.x * 4 + wave;   // global row = b*N + i
  if (row >= ROWS) return;
  const int b = row >> 11;        // / N (N=2048)
  const int i = row & (Nc - 1);   // % N

  const float* __restrict__ Arow = A   + (size_t)row * Nc;
  const float* __restrict__ Wh2b = Wh2 + (size_t)b * Nc;
  const float* __restrict__ Whb  = Wh  + (size_t)b * Nc * Hc;
  const float wh1 = Wh1[row];

  float m = -INFINITY, l = 0.f, acc0 = 0.f, acc1 = 0.f;

  for (int jc = 0; jc < Nc; jc += 64) {
    const int j = jc + lane;
    const float aval = Arow[j];
    const float mult = aval + ((j == i) ? 1.f : 0.f);  // A_ = A + I, in {0,1,2}
    float s = -INFINITY;
    if (mult > 0.f) {
      const float raw = wh1 + Wh2b[j];
      const float lr  = (raw >= 0.f) ? raw : LRELU_ALPHA * raw;
      s = mult * lr;                 // leakyrelu(mult*raw) == mult*leakyrelu(raw)
    }
    unsigned long long ball = __ballot(mult > 0.f);
    if (ball == 0ull) continue;

    // chunk max -> online rescale
    float cm = s;
#pragma unroll
    for (int off = 32; off > 0; off >>= 1) cm = fmaxf(cm, __shfl_xor(cm, off));
    if (cm > m) {
      const float sc = __expf(m - cm);   // first time: exp(-inf)=0
      l *= sc; acc0 *= sc; acc1 *= sc;
      m = cm;
    }
    // accumulate each nonzero: all 64 lanes cooperate on the 128-wide Wh row
    while (ball) {
      const int src = __ffsll(ball) - 1;
      ball &= (ball - 1ull);
      const float sj = __shfl(s, src);
      const float p  = __expf(sj - m);
      l += p;
      const float* __restrict__ wr = Whb + (size_t)(jc + src) * Hc;
      acc0 = fmaf(p, wr[lane], acc0);
      acc1 = fmaf(p, wr[64 + lane], acc1);
    }
  }

  const float inv = 1.f / l;   // l > 0: diagonal always present
  const float h0 = acc0 * inv;
  const float h1 = acc1 * inv;
  out[(size_t)row * Hc + lane]      = (h0 > 0.f) ? h0 : expm1f(h0);
  out[(size_t)row * Hc + 64 + lane] = (h1 > 0.f) ? h1 : expm1f(h1);
}

extern "C" void kernel_launch(void* const* d_in, const int* in_sizes, int n_in,
                              void* d_out, int out_size, void* d_ws, size_t ws_size,
                              hipStream_t stream) {
  const float* inp = (const float*)d_in[0];   // [B,N,H]
  const float* A   = (const float*)d_in[1];   // [B,N,N]
  const float* W   = (const float*)d_in[2];   // [H,H]
  const float* a   = (const float*)d_in[3];   // [2H,1]
  float* out = (float*)d_out;

  float* Wh  = (float*)d_ws;                  // ROWS*H floats = 8 MB
  float* Wh1 = Wh  + (size_t)ROWS * Hc;       // ROWS floats
  float* Wh2 = Wh1 + ROWS;                    // ROWS floats

  dim3 blk(256);
  dim3 grd(ROWS / 4);
  wh_kernel<<<grd, blk, 0, stream>>>(inp, W, a, Wh, Wh1, Wh2);
  attn_kernel<<<grd, blk, 0, stream>>>(A, Wh, Wh1, Wh2, out);
}

// Round 2
// 285.761 us; speedup vs baseline: 1.3797x; 1.3797x over previous
//
#include <hip/hip_runtime.h>
#include <hip/hip_bf16.h>
#include <math.h>

typedef __attribute__((ext_vector_type(4))) float f32x4;
typedef __attribute__((ext_vector_type(8))) short s16x8;

constexpr int Bc = 8;
constexpr int Nc = 2048;
constexpr int Hc = 128;
constexpr int ROWS = Bc * Nc;   // 16384

__device__ inline unsigned short f2bf(float f) {
  unsigned u = __float_as_uint(f);
  unsigned r = u + 0x7fffu + ((u >> 16) & 1u);   // RNE round to bf16
  return (unsigned short)(r >> 16);
}

// ---------------------------------------------------------------------------
// Kernel 1: Wh = inp @ W ; emit WhbfT[b][h][n] (bf16, transposed), wh1, wh2.
// Block: 256 threads, 32 rows. W + x staged in LDS (80KB -> 2 blocks/CU).
// ---------------------------------------------------------------------------
__global__ __launch_bounds__(256, 2) void wh_kernel(
    const float* __restrict__ inp, const float* __restrict__ W,
    const float* __restrict__ a,
    unsigned short* __restrict__ WhbfT,   // [B][H][N] bf16 bits
    float* __restrict__ Wh1, float* __restrict__ Wh2) {
  __shared__ float Wlds[128 * 128];   // 64KB, [k][h]
  __shared__ float xlds[32 * 128];    // 16KB, [r][k]; reused as transpose tile

  const int t  = threadIdx.x;
  const int w_ = t >> 6;
  const int l  = t & 63;
  const int rbase_g = blockIdx.x * 32;   // global row base

  // stage W and x
  {
    const f32x4* W4 = (const f32x4*)W;
    f32x4* Wl4 = (f32x4*)Wlds;
#pragma unroll
    for (int i = 0; i < 16; ++i) Wl4[t + 256 * i] = W4[t + 256 * i];
    const f32x4* X4 = (const f32x4*)(inp + (size_t)rbase_g * Hc);
    f32x4* xl4 = (f32x4*)xlds;
#pragma unroll
    for (int i = 0; i < 4; ++i) xl4[t + 256 * i] = X4[t + 256 * i];
  }
  __syncthreads();

  float acc0[8], acc1[8];
#pragma unroll
  for (int r = 0; r < 8; ++r) { acc0[r] = 0.f; acc1[r] = 0.f; }

  for (int k4 = 0; k4 < 128; k4 += 4) {
    f32x4 xv[8];
#pragma unroll
    for (int r = 0; r < 8; ++r)
      xv[r] = *(const f32x4*)&xlds[(w_ * 8 + r) * 128 + k4];
#pragma unroll
    for (int i = 0; i < 4; ++i) {
      const float w0 = Wlds[(k4 + i) * 128 + l];
      const float w1 = Wlds[(k4 + i) * 128 + 64 + l];
#pragma unroll
      for (int r = 0; r < 8; ++r) {
        acc0[r] = fmaf(xv[r][i], w0, acc0[r]);
        acc1[r] = fmaf(xv[r][i], w1, acc1[r]);
      }
    }
  }

  // wh1/wh2 projections
  {
    const float a0 = a[l], a1 = a[64 + l], a2 = a[128 + l], a3 = a[192 + l];
#pragma unroll
    for (int r = 0; r < 8; ++r) {
      float p1 = acc0[r] * a0 + acc1[r] * a1;
      float p2 = acc0[r] * a2 + acc1[r] * a3;
#pragma unroll
      for (int off = 32; off > 0; off >>= 1) {
        p1 += __shfl_xor(p1, off);
        p2 += __shfl_xor(p2, off);
      }
      if (l == 0) {
        Wh1[rbase_g + w_ * 8 + r] = p1;
        Wh2[rbase_g + w_ * 8 + r] = p2;
      }
    }
  }

  // transpose to bf16 via LDS (reuse xlds). T[h][rp] u32, stride 18 words.
  __syncthreads();
  unsigned* T = (unsigned*)xlds;
#pragma unroll
  for (int i = 0; i < 4; ++i) {   // row pairs (2i,2i+1) within this wave
    unsigned v0 = (unsigned)f2bf(acc0[2 * i]) | ((unsigned)f2bf(acc0[2 * i + 1]) << 16);
    unsigned v1 = (unsigned)f2bf(acc1[2 * i]) | ((unsigned)f2bf(acc1[2 * i + 1]) << 16);
    T[l * 18 + (w_ * 4 + i)]        = v0;
    T[(64 + l) * 18 + (w_ * 4 + i)] = v1;
  }
  __syncthreads();

  // write out: thread -> (h = t>>1, half = t&1), 8 words = 32B
  {
    const int h = t >> 1, half = t & 1;
    const int bq = rbase_g >> 11;          // batch
    const int n0 = rbase_g & 2047;         // row offset in batch
    unsigned wv[8];
#pragma unroll
    for (int c = 0; c < 8; ++c) wv[c] = T[h * 18 + half * 8 + c];
    unsigned short* dst = WhbfT + ((size_t)bq * 128 + h) * 2048 + n0 + half * 16;
    uint4 u0 = make_uint4(wv[0], wv[1], wv[2], wv[3]);
    uint4 u1 = make_uint4(wv[4], wv[5], wv[6], wv[7]);
    *(uint4*)dst = u0;
    *(uint4*)(dst + 8) = u1;
  }
}

// ---------------------------------------------------------------------------
// Kernel 2: flash-style masked softmax + P@Wh (MFMA bf16) + ELU.
// Block: 256 threads / 4 waves, 16 Q-rows; waves split the 32 j-tiles (8 ea).
// ---------------------------------------------------------------------------
#define LOADT(TILE, AV, WV) do {                              \
    const int jb_ = (TILE) * 64 + g8;                         \
    AV[0] = *(const f32x4*)(Arow + jb_);                      \
    AV[1] = *(const f32x4*)(Arow + jb_ + 4);                  \
    AV[2] = *(const f32x4*)(Arow + jb_ + 32);                 \
    AV[3] = *(const f32x4*)(Arow + jb_ + 36);                 \
    WV[0] = *(const f32x4*)(Wh2b + jb_);                      \
    WV[1] = *(const f32x4*)(Wh2b + jb_ + 4);                  \
    WV[2] = *(const f32x4*)(Wh2b + jb_ + 32);                 \
    WV[3] = *(const f32x4*)(Wh2b + jb_ + 36);                 \
  } while (0)

__global__ __launch_bounds__(256, 3) void attn_kernel(
    const float* __restrict__ A, const unsigned short* __restrict__ WhbfT,
    const float* __restrict__ Wh1, const float* __restrict__ Wh2,
    float* __restrict__ out) {
  __shared__ float lds_m[64], lds_l[64];
  __shared__ float accbuf[16 * 132];

  const int t  = threadIdx.x;
  const int w_ = t >> 6;
  const int l  = t & 63;
  const int bid = blockIdx.x;            // 16-row group id (0..1023)
  const int b    = bid >> 7;             // batch
  const int rloc = (bid & 127) * 16;     // row base within batch
  const int g8 = (l >> 4) * 8;
  const int irow = rloc + (l & 15);      // this lane's local row (for diag)

  const float* Arow = A + ((size_t)bid * 16 + (l & 15)) * 2048;
  const float* Wh2b = Wh2 + (size_t)b * 2048;
  const float wh1r = Wh1[(size_t)bid * 16 + (l & 15)];
  const unsigned short* WTl = WhbfT + ((size_t)b * 128 + (l & 15)) * 2048 + g8;

  f32x4 acc[8];
  const f32x4 zero = {0.f, 0.f, 0.f, 0.f};
#pragma unroll
  for (int nb = 0; nb < 8; ++nb) acc[nb] = zero;
  float m = -1e30f, lsum = 0.f;

  f32x4 avbuf[2][4], wvbuf[2][4];
  LOADT(w_, avbuf[0], wvbuf[0]);

#pragma unroll 2
  for (int t8 = 0; t8 < 8; ++t8) {
    const int tile = t8 * 4 + w_;
    const int jb0 = tile * 64;
    if (t8 < 7) LOADT(tile + 4, avbuf[(t8 + 1) & 1], wvbuf[(t8 + 1) & 1]);

    // scores s[16]: idx -> (sub=idx>>3, e=idx&7), j = jb0+sub*32+g8+e
    float s[16];
    float tm = -3e30f;
#pragma unroll
    for (int idx = 0; idx < 16; ++idx) {
      const int j = jb0 + (idx >> 3) * 32 + g8 + (idx & 7);
      const float aval = avbuf[t8 & 1][idx >> 2][idx & 3];
      const float raw  = wh1r + wvbuf[t8 & 1][idx >> 2][idx & 3];
      const float lr   = fmaxf(raw, 0.2f * raw);
      const float mult = aval + ((j == irow) ? 1.0f : 0.0f);
      const float sv   = (mult > 0.f) ? mult * lr : -2e30f;
      s[idx] = sv;
      tm = fmaxf(tm, sv);
    }
    tm = fmaxf(tm, __shfl_xor(tm, 16));
    tm = fmaxf(tm, __shfl_xor(tm, 32));
    const float mnew = (tm > m + 8.f) ? tm : m;   // defer-max threshold
    if (__ballot(mnew != m)) {
      const float alpha = __expf(m - mnew);       // ==1 for unchanged rows
      lsum *= alpha;
      float ad[4];
#pragma unroll
      for (int rg = 0; rg < 4; ++rg) ad[rg] = __shfl(alpha, (l >> 4) * 4 + rg);
#pragma unroll
      for (int nb = 0; nb < 8; ++nb) {
#pragma unroll
        for (int rg = 0; rg < 4; ++rg) acc[nb][rg] *= ad[rg];
      }
      m = mnew;
    }

    float tsum = 0.f;
    s16x8 pa0, pa1;
#pragma unroll
    for (int idx = 0; idx < 16; ++idx) {
      const float p = __expf(s[idx] - m);   // masked: exp(<=-1e30)=0
      tsum += p;
      if (idx < 8) pa0[idx] = (short)f2bf(p);
      else         pa1[idx - 8] = (short)f2bf(p);
    }
    tsum += __shfl_xor(tsum, 16);
    tsum += __shfl_xor(tsum, 32);
    lsum += tsum;

#pragma unroll
    for (int nb = 0; nb < 8; ++nb) {
      const unsigned short* vp = WTl + (size_t)nb * 16 * 2048 + jb0;
      const s16x8 v0 = *(const s16x8*)vp;
      const s16x8 v1 = *(const s16x8*)(vp + 32);
      acc[nb] = __builtin_amdgcn_mfma_f32_16x16x32_bf16(pa0, v0, acc[nb], 0, 0, 0);
      acc[nb] = __builtin_amdgcn_mfma_f32_16x16x32_bf16(pa1, v1, acc[nb], 0, 0, 0);
    }
  }

  // ---- merge the 4 waves' partial (m, l, acc) ----
  if (l < 16) { lds_m[w_ * 16 + l] = m; lds_l[w_ * 16 + l] = lsum; }
  __syncthreads();

  float beta[4], lstar[4];
#pragma unroll
  for (int rg = 0; rg < 4; ++rg) {
    const int rd = (l >> 4) * 4 + rg;
    const float m0 = lds_m[rd],      m1 = lds_m[16 + rd];
    const float m2 = lds_m[32 + rd], m3 = lds_m[48 + rd];
    const float ms = fmaxf(fmaxf(m0, m1), fmaxf(m2, m3));
    lstar[rg] = lds_l[rd] * __expf(m0 - ms) + lds_l[16 + rd] * __expf(m1 - ms)
              + lds_l[32 + rd] * __expf(m2 - ms) + lds_l[48 + rd] * __expf(m3 - ms);
    beta[rg] = __expf(lds_m[w_ * 16 + rd] - ms);
  }
#pragma unroll
  for (int nb = 0; nb < 8; ++nb) {
#pragma unroll
    for (int rg = 0; rg < 4; ++rg) acc[nb][rg] *= beta[rg];
  }

  if (w_ == 3) {
#pragma unroll
    for (int nb = 0; nb < 8; ++nb)
#pragma unroll
      for (int rg = 0; rg < 4; ++rg)
        accbuf[((l >> 4) * 4 + rg) * 132 + nb * 16 + (l & 15)] = acc[nb][rg];
  }
  __syncthreads();
  if (w_ == 2) {
#pragma unroll
    for (int nb = 0; nb < 8; ++nb)
#pragma unroll
      for (int rg = 0; rg < 4; ++rg)
        accbuf[((l >> 4) * 4 + rg) * 132 + nb * 16 + (l & 15)] += acc[nb][rg];
  }
  __syncthreads();
  if (w_ == 1) {
#pragma unroll
    for (int nb = 0; nb < 8; ++nb)
#pragma unroll
      for (int rg = 0; rg < 4; ++rg)
        accbuf[((l >> 4) * 4 + rg) * 132 + nb * 16 + (l & 15)] += acc[nb][rg];
  }
  __syncthreads();
  if (w_ == 0) {
    float* outp = out + ((size_t)bid * 16) * 128;
#pragma unroll
    for (int nb = 0; nb < 8; ++nb) {
#pragma unroll
      for (int rg = 0; rg < 4; ++rg) {
        const int rd = (l >> 4) * 4 + rg;
        float v = (accbuf[rd * 132 + nb * 16 + (l & 15)] + acc[nb][rg]) / lstar[rg];
        v = (v > 0.f) ? v : expm1f(v);
        outp[rd * 128 + nb * 16 + (l & 15)] = v;
      }
    }
  }
}

extern "C" void kernel_launch(void* const* d_in, const int* in_sizes, int n_in,
                              void* d_out, int out_size, void* d_ws, size_t ws_size,
                              hipStream_t stream) {
  const float* inp = (const float*)d_in[0];   // [B,N,H]
  const float* A   = (const float*)d_in[1];   // [B,N,N]
  const float* W   = (const float*)d_in[2];   // [H,H]
  const float* a   = (const float*)d_in[3];   // [2H,1]
  float* out = (float*)d_out;

  unsigned short* WhbfT = (unsigned short*)d_ws;                    // 4MB bf16 [B][H][N]
  float* Wh1 = (float*)((char*)d_ws + (size_t)Bc * Hc * Nc * 2);    // 64KB
  float* Wh2 = Wh1 + ROWS;                                          // 64KB

  wh_kernel<<<dim3(ROWS / 32), dim3(256), 0, stream>>>(inp, W, a, WhbfT, Wh1, Wh2);
  attn_kernel<<<dim3(ROWS / 16), dim3(256), 0, stream>>>(A, WhbfT, Wh1, Wh2, out);
}